// Round 5
// baseline (570.883 us; speedup 1.0000x reference)
//
#include <hip/hip_runtime.h>

// Problem constants (fixed by reference)
#define HH   480
#define WW   640
#define HWP  (HH*WW)      // 307200
#define NSEM 12
#define NINS 16
#define NCH  28           // sem channels then ins channels

// ---------------------------------------------------------------------------
// bf16 helpers (raw ushort storage, RNE rounding)
// ---------------------------------------------------------------------------
__device__ __forceinline__ float bf2f(unsigned short u) {
    return __uint_as_float(((unsigned int)u) << 16);
}
__device__ __forceinline__ unsigned short f2bf(float f) {
    unsigned int b = __float_as_uint(f);
    return (unsigned short)((b + 0x7FFFu + ((b >> 16) & 1u)) >> 16);
}

// ---------------------------------------------------------------------------
// 13-tap Gaussian (sigma=3, r=6)
// ---------------------------------------------------------------------------
__device__ __forceinline__ void gauss13(float k[13]) {
    float s = 0.f;
#pragma unroll
    for (int j = 0; j < 13; ++j) {
        float xx = (float)(j - 6);
        float v  = __expf(-(xx * xx) * (1.f / 18.f));
        k[j] = v; s += v;
    }
    float inv = 1.f / s;
#pragma unroll
    for (int j = 0; j < 13; ++j) k[j] *= inv;
}

template <int N>
__device__ __forceinline__ void softmaxN(const float* __restrict__ in, float* __restrict__ out) {
    float m = in[0];
#pragma unroll
    for (int i = 1; i < N; ++i) m = fmaxf(m, in[i]);
    float s = 0.f;
#pragma unroll
    for (int i = 0; i < N; ++i) { float e = __expf(in[i] - m); out[i] = e; s += e; }
    float inv = 1.f / s;
#pragma unroll
    for (int i = 0; i < N; ++i) out[i] *= inv;
}

// ---------------------------------------------------------------------------
// Init: softmax(logits) -> q (bf16)
// ---------------------------------------------------------------------------
__global__ __launch_bounds__(256) void init_kernel(const float* __restrict__ semL,
                                                   const float* __restrict__ insL,
                                                   unsigned short* __restrict__ q) {
    int p = blockIdx.x * 256 + threadIdx.x;
    float v[NINS], o[NINS];
#pragma unroll
    for (int i = 0; i < NSEM; ++i) v[i] = semL[i * HWP + p];
    softmaxN<NSEM>(v, o);
#pragma unroll
    for (int i = 0; i < NSEM; ++i) q[i * HWP + p] = f2bf(o[i]);
#pragma unroll
    for (int i = 0; i < NINS; ++i) v[i] = insL[i * HWP + p];
    softmaxN<NINS>(v, o);
#pragma unroll
    for (int i = 0; i < NINS; ++i) q[(NSEM + i) * HWP + p] = f2bf(o[i]);
}

// ---------------------------------------------------------------------------
// Fused separable 13x13 blur (zero pad), LDS-tiled 64x32, bf16 in/out
// ---------------------------------------------------------------------------
#define BTW 64
#define BTH 32
#define BR  6
__global__ __launch_bounds__(256) void blur_fused_kernel(const unsigned short* __restrict__ in,
                                                         unsigned short* __restrict__ out) {
    __shared__ float raw[(BTH + 2 * BR) * (BTW + 2 * BR)];  // 44*76 fp32
    __shared__ float hb[(BTH + 2 * BR) * BTW];              // 44*64 fp32
    const int t  = threadIdx.x;
    const int x0 = blockIdx.x * BTW;
    const int y0 = blockIdx.y * BTH;
    const int c  = blockIdx.z;
    const unsigned short* __restrict__ plane = in + (size_t)c * HWP;

    float k[13]; gauss13(k);

    const int RAWW = BTW + 2 * BR;            // 76
    const int RAWN = RAWW * (BTH + 2 * BR);   // 3344
    for (int idx = t; idx < RAWN; idx += 256) {
        int ly = idx / RAWW, lx = idx - ly * RAWW;
        int gy = y0 - BR + ly, gx = x0 - BR + lx;
        float v = 0.f;
        if (gy >= 0 && gy < HH && gx >= 0 && gx < WW) v = bf2f(plane[gy * WW + gx]);
        raw[idx] = v;
    }
    __syncthreads();

    const int HBN = BTW * (BTH + 2 * BR);     // 2816
    for (int idx = t; idx < HBN; idx += 256) {
        int ly = idx / BTW, lx = idx - ly * BTW;
        const float* r = raw + ly * RAWW + lx;
        float acc = 0.f;
#pragma unroll
        for (int j = 0; j < 13; ++j) acc = fmaf(k[j], r[j], acc);
        hb[idx] = acc;
    }
    __syncthreads();

    for (int idx = t; idx < BTW * BTH; idx += 256) {
        int ly = idx / BTW, lx = idx - ly * BTW;
        const float* hcol = hb + ly * BTW + lx;
        float acc = 0.f;
#pragma unroll
        for (int j = 0; j < 13; ++j) acc = fmaf(k[j], hcol[j * BTW], acc);
        out[(size_t)c * HWP + (y0 + ly) * WW + (x0 + lx)] = f2bf(acc);
    }
}

// ---------------------------------------------------------------------------
// Fused iteration tail. 32x8 pixel tile / 256 threads (halo amp 1.69x).
// q/sp streams bf16; logits read as ORIGINAL fp32 (accuracy-critical, they
// are a systematic bias re-injected every iteration — no filter averaging).
// fp32 LDS staging; bilateral weights recomputed from LDS image window.
// ---------------------------------------------------------------------------
#define TTW 32
#define TTH 8
#define GC  7
#define NG  (NCH / GC)        // 4
#define TWW (TTW + 4)         // 36
#define TWH (TTH + 4)         // 12
#define TWN (TWW * TWH)       // 432
#define GN  (GC * TWN)        // 3024
#define NSLOT ((GN + 255) / 256)  // 12

template <bool OUTBF>
__global__ __launch_bounds__(256) void tail_kernel(const unsigned short* __restrict__ qin,
                                                   const unsigned short* __restrict__ sp,
                                                   const float* __restrict__ img,
                                                   const float* __restrict__ semL,
                                                   const float* __restrict__ insL,
                                                   const float* __restrict__ sem_sw,
                                                   const float* __restrict__ sem_bw,
                                                   const float* __restrict__ sem_compat,
                                                   const float* __restrict__ ins_sw,
                                                   const float* __restrict__ ins_bw,
                                                   const int*   __restrict__ labels,
                                                   const float* __restrict__ cross_is,
                                                   const float* __restrict__ cross_si,
                                                   void* __restrict__ qout_v) {
    __shared__ float lq[GN];             // 12096 B
    __shared__ float limg[3 * TWN];      // 5184 B
    __shared__ float sC[NSEM * NSEM];
    __shared__ float sMis[NINS * NSEM];
    __shared__ float sMsi[NINS * NSEM];
    __shared__ float sws[NSEM], sbs[NSEM], swi[NINS], sbi[NINS];

    const int t  = threadIdx.x;
    const int tx = t & 31;
    const int ty = t >> 5;
    const int x0 = blockIdx.x * TTW;
    const int y0 = blockIdx.y * TTH;
    const int p  = (y0 + ty) * WW + (x0 + tx);

    if (t < NSEM * NSEM) sC[t] = sem_compat[t];
    if (t < NINS * NSEM) {
        int i = t / NSEM, o = t - i * NSEM;
        sMis[t] = cross_is[labels[i] * NSEM + o];
        sMsi[t] = cross_si[labels[i] * NSEM + o];  // [o_ins*12 + i_sem]
    }
    if (t < NSEM) { sws[t] = sem_sw[t]; sbs[t] = sem_bw[t]; }
    if (t < NINS) { int l = labels[t]; swi[t] = ins_sw[l]; sbi[t] = ins_bw[l]; }

    // staging offsets (identical clamped gy/gx for every channel group)
    int goff[NSLOT];
#pragma unroll
    for (int j = 0; j < NSLOT; ++j) {
        int idx = t + j * 256;
        if (idx < GN) {
            int cc  = idx / TWN;
            int rem = idx - cc * TWN;
            int ly  = rem / TWW, lx = rem - ly * TWW;
            int gy  = min(max(y0 - 2 + ly, 0), HH - 1);
            int gx  = min(max(x0 - 2 + lx, 0), WW - 1);
            goff[j] = cc * HWP + gy * WW + gx;
        } else goff[j] = 0;
    }

    // stage image window (fp32) + q group 0
    for (int idx = t; idx < 3 * TWN; idx += 256) {
        int cc  = idx / TWN;
        int rem = idx - cc * TWN;
        int ly  = rem / TWW, lx = rem - ly * TWW;
        int gy  = min(max(y0 - 2 + ly, 0), HH - 1);
        int gx  = min(max(x0 - 2 + lx, 0), WW - 1);
        limg[idx] = img[(size_t)cc * HWP + gy * WW + gx];
    }
#pragma unroll
    for (int j = 0; j < NSLOT; ++j) {
        int idx = t + j * 256;
        if (idx < GN) lq[idx] = bf2f(qin[goff[j]]);
    }
    __syncthreads();

    // per-pixel bilateral weights from staged image window
    const int wc = (ty + 2) * TWW + (tx + 2);
    float i0 = limg[wc], i1 = limg[TWN + wc], i2 = limg[2 * TWN + wc];
    float wnr[25];
    {
        float den = 0.f;
        int d = 0;
#pragma unroll
        for (int dy = 0; dy < 5; ++dy) {
#pragma unroll
            for (int dx = 0; dx < 5; ++dx) {
                int nb = (ty + dy) * TWW + (tx + dx);
                float d0 = limg[nb] - i0;
                float d1 = limg[TWN + nb] - i1;
                float d2 = limg[2 * TWN + nb] - i2;
                float cd = d0 * d0 + d1 * d1 + d2 * d2;
                float sd = (float)((dy - 2) * (dy - 2) + (dx - 2) * (dx - 2));
                float wv = __expf(-sd * (1.f / 18.f) - cd * (1.f / 0.045f));
                wnr[d++] = wv; den += wv;
            }
        }
        float inv = 1.f / den;
#pragma unroll
        for (int j = 0; j < 25; ++j) wnr[j] *= inv;
    }

    // bilateral gather over channel groups (single LDS buffer)
    float bl[NCH];
#pragma unroll
    for (int c = 0; c < NCH; ++c) bl[c] = 0.f;

    for (int g = 0; g < NG; ++g) {
        const int c0 = g * GC;
#pragma unroll
        for (int cc = 0; cc < GC; ++cc) {
            const float* w0 = lq + cc * TWN + ty * TWW + tx;
            float a = 0.f;
            int d = 0;
#pragma unroll
            for (int dy = 0; dy < 5; ++dy)
#pragma unroll
                for (int dx = 0; dx < 5; ++dx)
                    a = fmaf(wnr[d++], w0[dy * TWW + dx], a);
            bl[c0 + cc] = a;
        }
        __syncthreads();  // all reads of lq done
        if (g + 1 < NG) {
            const unsigned short* pl = qin + (size_t)(g + 1) * GC * HWP;
#pragma unroll
            for (int j = 0; j < NSLOT; ++j) {
                int idx = t + j * 256;
                if (idx < GN) lq[idx] = bf2f(pl[goff[j]]);
            }
            __syncthreads();  // staged writes visible
        }
    }

    // pointwise tail (logits in fp32)
    float comb[NSEM];
#pragma unroll
    for (int i = 0; i < NSEM; ++i)
        comb[i] = sws[i] * bf2f(sp[i * HWP + p]) + sbs[i] * bl[i];
    float ts[NSEM];
#pragma unroll
    for (int o = 0; o < NSEM; ++o) {
        float a = semL[o * HWP + p];
#pragma unroll
        for (int i = 0; i < NSEM; ++i) a = fmaf(sC[i * NSEM + o], comb[i], a);
        ts[o] = a;
    }

    float ti[NINS];
#pragma unroll
    for (int i = 0; i < NINS; ++i)
        ti[i] = insL[i * HWP + p] + swi[i] * bf2f(sp[(NSEM + i) * HWP + p]) + sbi[i] * bl[NSEM + i];

    float sIns[NINS], sSem[NSEM];
    softmaxN<NINS>(ti, sIns);
    softmaxN<NSEM>(ts, sSem);

    float nts[NSEM];
#pragma unroll
    for (int o = 0; o < NSEM; ++o) {
        float a = ts[o];
#pragma unroll
        for (int i = 0; i < NINS; ++i) a = fmaf(sMis[i * NSEM + o], sIns[i], a);
        nts[o] = a;
    }
    float nti[NINS];
#pragma unroll
    for (int o = 0; o < NINS; ++o) {
        float a = ti[o];
#pragma unroll
        for (int i = 0; i < NSEM; ++i) a = fmaf(sMsi[o * NSEM + i], sSem[i], a);
        nti[o] = a;
    }

    float oq[NINS];
    softmaxN<NSEM>(nts, oq);
#pragma unroll
    for (int i = 0; i < NSEM; ++i) {
        if (OUTBF) ((unsigned short*)qout_v)[i * HWP + p] = f2bf(oq[i]);
        else       ((float*)qout_v)[i * HWP + p] = oq[i];
    }
    softmaxN<NINS>(nti, oq);
#pragma unroll
    for (int i = 0; i < NINS; ++i) {
        if (OUTBF) ((unsigned short*)qout_v)[(NSEM + i) * HWP + p] = f2bf(oq[i]);
        else       ((float*)qout_v)[(NSEM + i) * HWP + p] = oq[i];
    }
}

// ---------------------------------------------------------------------------
extern "C" void kernel_launch(void* const* d_in, const int* in_sizes, int n_in,
                              void* d_out, int out_size, void* d_ws, size_t ws_size,
                              hipStream_t stream) {
    const float* image      = (const float*)d_in[0];
    const float* semL       = (const float*)d_in[1];
    const float* insL       = (const float*)d_in[2];
    const int*   labels     = (const int*)  d_in[3];
    const float* sem_sw     = (const float*)d_in[4];
    const float* sem_bw     = (const float*)d_in[5];
    const float* sem_compat = (const float*)d_in[6];
    const float* ins_sw     = (const float*)d_in[7];
    const float* ins_bw     = (const float*)d_in[8];
    const float* cross_is   = (const float*)d_in[9];
    const float* cross_si   = (const float*)d_in[10];

    // Workspace (bf16 ushort): A[28HW] | B[28HW] | S[28HW]
    unsigned short* ws = (unsigned short*)d_ws;
    unsigned short* A  = ws;
    unsigned short* B  = A + (size_t)NCH * HWP;
    unsigned short* S  = B + (size_t)NCH * HWP;

    const int PIX_BLOCKS = HWP / 256;  // 1200

    init_kernel<<<PIX_BLOCKS, 256, 0, stream>>>(semL, insL, A);

    dim3 bgrid(WW / BTW, HH / BTH, NCH);    // 10 x 15 x 28
    dim3 tgrid(WW / TTW, HH / TTH);         // 20 x 60

    unsigned short* qin[3] = { A, B, A };
    for (int it = 0; it < 3; ++it) {
        blur_fused_kernel<<<bgrid, 256, 0, stream>>>(qin[it], S);
        if (it < 2) {
            unsigned short* qo = (it == 0) ? B : A;
            tail_kernel<true><<<tgrid, 256, 0, stream>>>(qin[it], S, image, semL, insL,
                                                         sem_sw, sem_bw, sem_compat,
                                                         ins_sw, ins_bw, labels,
                                                         cross_is, cross_si, (void*)qo);
        } else {
            tail_kernel<false><<<tgrid, 256, 0, stream>>>(qin[it], S, image, semL, insL,
                                                          sem_sw, sem_bw, sem_compat,
                                                          ins_sw, ins_bw, labels,
                                                          cross_is, cross_si, d_out);
        }
    }
}